// Round 12
// baseline (282.635 us; speedup 1.0000x reference)
//
#include <hip/hip_runtime.h>

// AttentionBlock: B=8, N=4096, C=256, fp32 in/out.
// Pipeline: [wt_prep][qkv gemm f16][flash attn 32x32x16 f16][proj gemm+combine]
// R12 (attn only): T3/T4 counted-vmcnt pipeline. Ring-3 LDS (96KB), 2-deep
// DMA prefetch, per-iter "s_waitcnt vmcnt(4); s_barrier" instead of
// __syncthreads' vmcnt(0) drain -> tile kt+1's loads stay in flight across
// the barrier (the m97-analysis ~20% drain stall; +38-73% on 8-phase GEMM).
// WAR safe: buffer overwritten at iter kt was last read at iter kt-1, all
// reads complete before this barrier; ds_reads consumed by MFMAs pre-barrier.
// GEMMs: R6 M=128 2-barrier staged (proven best). XCD swizzle kept (R8).
// Evidence ledger (R1-R11): 2 waves/SIMD optimum; 4 waves spills (R10);
// dbuf GEMM/B-global/block-split/64-key tiles all regressed.
// Workspace: q 16MB | k 16MB | vt 16MB | opart f16 32MB | wt 512KB | l 256KB

typedef _Float16 half8 __attribute__((ext_vector_type(8)));
typedef _Float16 half4 __attribute__((ext_vector_type(4)));
typedef float f32x4 __attribute__((ext_vector_type(4)));
typedef float f32x16 __attribute__((ext_vector_type(16)));
typedef unsigned int u32x4 __attribute__((ext_vector_type(4)));
typedef unsigned int u32x2 __attribute__((ext_vector_type(2)));

#define MFMA16(a, b, c) __builtin_amdgcn_mfma_f32_16x16x32_f16((a), (b), (c), 0, 0, 0)
#define MFMA32(a, b, c) __builtin_amdgcn_mfma_f32_32x32x16_f16((a), (b), (c), 0, 0, 0)

#if __has_builtin(__builtin_amdgcn_exp2f)
#define EXP2(x) __builtin_amdgcn_exp2f(x)
#else
#define EXP2(x) exp2f(x)
#endif

// log2(e)/16 folded into q; exp(s-8) == exp2(s' - 8*log2e)
#define QSCALE 0.09016843898f
#define ESHIFT 11.5415603f

__device__ __forceinline__ void lds_load16(const void* g, void* l) {
    __builtin_amdgcn_global_load_lds(
        (const __attribute__((address_space(1))) unsigned int*)g,
        (__attribute__((address_space(3))) unsigned int*)l, 16, 0, 0);
}

// ---------------------------------------------------------------------------
// Weight prep: Wt[z][n][k] f16 = W_z[k][n] f32, 4 weights of 256x256.
// ---------------------------------------------------------------------------
__global__ __launch_bounds__(256)
void wt_prep(const float* __restrict__ w0, const float* __restrict__ w1,
             const float* __restrict__ w2, const float* __restrict__ w3,
             _Float16* __restrict__ outw)
{
    __shared__ _Float16 sT[64 * 72];
    const int z = blockIdx.z;
    const float* W = (z == 0) ? w0 : (z == 1) ? w1 : (z == 2) ? w2 : w3;
    _Float16* O = outw + z * 65536;
    const int kb = blockIdx.x * 64, nb = blockIdx.y * 64;
    const int t = threadIdx.x;
    const int r = t >> 4, c4 = (t & 15) * 4;
#pragma unroll
    for (int i = 0; i < 4; ++i) {
        f32x4 ld = *(const f32x4*)(W + (size_t)(kb + r + i * 16) * 256 + nb + c4);
#pragma unroll
        for (int j = 0; j < 4; ++j) sT[(c4 + j) * 72 + r + i * 16] = (_Float16)ld[j];
    }
    __syncthreads();
#pragma unroll
    for (int i = 0; i < 4; ++i) {
        int n = r + i * 16;
        *(u32x2*)&O[(size_t)(nb + n) * 256 + kb + c4] = *(const u32x2*)&sT[n * 72 + c4];
    }
}

// ---------------------------------------------------------------------------
// Fused QKV GEMM (M=128): x f32 -> q,k f16 row-major; v -> f16 vt[b][ch][pix].
// Per iter: stage A 128x32 + 3x B 64x32 into LDS (2 barriers), then per wave
// 8 A-frags x 3 B-frags -> 24 MFMA16. Wave w owns col-tile w of all 3 outputs.
// ---------------------------------------------------------------------------
__global__ __launch_bounds__(256)
void qkv_gemm(const float* __restrict__ x, const _Float16* __restrict__ wt,
              const float* __restrict__ bq, const float* __restrict__ bk,
              const float* __restrict__ bv,
              _Float16* __restrict__ qo, _Float16* __restrict__ ko,
              _Float16* __restrict__ vo)
{
    __shared__ _Float16 smem[12800];   // sA[128][40] | 3 x sB[64][40]

    const int tid  = threadIdx.x;
    const int w    = tid >> 6;
    const int lane = tid & 63;
    const int quad = lane >> 4;
    const int l16  = lane & 15;
    const int m0   = blockIdx.x * 128;
    const int n0   = blockIdx.y * 64;
    const int rA = tid >> 1, cA = (tid & 1) << 4;   // A staging: 2 thr/row, 16 ch
    const int rB = tid >> 2, cB = (tid & 3) << 3;   // B staging: 4 thr/row, 8 ch

    const float* ap = x + (size_t)(m0 + rA) * 256 + cA;
    f32x4 a0 = *(const f32x4*)ap,       a1 = *(const f32x4*)(ap + 4);
    f32x4 a2 = *(const f32x4*)(ap + 8), a3 = *(const f32x4*)(ap + 12);
    u32x4 bst[3];
#pragma unroll
    for (int o = 0; o < 3; ++o)
        bst[o] = *(const u32x4*)(wt + o * 65536 + (size_t)(n0 + rB) * 256 + cB);

    f32x4 zero4 = {0.f, 0.f, 0.f, 0.f};
    f32x4 acc[3][8];
#pragma unroll
    for (int o = 0; o < 3; ++o)
#pragma unroll
        for (int mt = 0; mt < 8; ++mt) acc[o][mt] = zero4;

    for (int it = 0; it < 8; ++it) {
        __syncthreads();
        half8 t0, t1;
#pragma unroll
        for (int j = 0; j < 4; ++j) {
            t0[j] = (_Float16)a0[j]; t0[j + 4] = (_Float16)a1[j];
            t1[j] = (_Float16)a2[j]; t1[j + 4] = (_Float16)a3[j];
        }
        *(half8*)&smem[rA * 40 + cA]     = t0;
        *(half8*)&smem[rA * 40 + cA + 8] = t1;
#pragma unroll
        for (int o = 0; o < 3; ++o)
            *(u32x4*)&smem[5120 + o * 2560 + rB * 40 + cB] = bst[o];
        __syncthreads();
        if (it < 7) {
            int k0 = (it + 1) * 32;
            const float* ap2 = x + (size_t)(m0 + rA) * 256 + k0 + cA;
            a0 = *(const f32x4*)ap2;       a1 = *(const f32x4*)(ap2 + 4);
            a2 = *(const f32x4*)(ap2 + 8); a3 = *(const f32x4*)(ap2 + 12);
#pragma unroll
            for (int o = 0; o < 3; ++o)
                bst[o] = *(const u32x4*)(wt + o * 65536 + (size_t)(n0 + rB) * 256 + k0 + cB);
        }
        half8 af[8];
#pragma unroll
        for (int mt = 0; mt < 8; ++mt)
            af[mt] = *(const half8*)&smem[(mt * 16 + l16) * 40 + quad * 8];
#pragma unroll
        for (int o = 0; o < 3; ++o) {
            half8 bf = *(const half8*)&smem[5120 + o * 2560 + (16 * w + l16) * 40 + quad * 8];
#pragma unroll
            for (int mt = 0; mt < 8; ++mt)
                acc[o][mt] = MFMA16(af[mt], bf, acc[o][mt]);
        }
    }

    const int col = n0 + 16 * w + l16;
#pragma unroll
    for (int mt = 0; mt < 8; ++mt) {
#pragma unroll
        for (int reg = 0; reg < 4; ++reg) {
            int row = m0 + 16 * mt + quad * 4 + reg;
            qo[(size_t)row * 256 + col] = (_Float16)((acc[0][mt][reg] + bq[col]) * QSCALE);
            ko[(size_t)row * 256 + col] = (_Float16)(acc[1][mt][reg] + bk[col]);
        }
    }
    __syncthreads();
    _Float16* sT = smem;   // 64 ch x 128 pix transpose staging (stride 136)
#pragma unroll
    for (int mt = 0; mt < 8; ++mt)
#pragma unroll
        for (int reg = 0; reg < 4; ++reg)
            sT[(16 * w + l16) * 136 + 16 * mt + quad * 4 + reg] =
                (_Float16)(acc[2][mt][reg] + bv[col]);
    __syncthreads();
    int ch = tid >> 2, po = (tid & 3) << 5;
    int bb = m0 >> 12, pix = m0 & 4095;
    _Float16* dst = vo + (size_t)bb * 1048576 + (size_t)(n0 + ch) * 4096 + pix + po;
#pragma unroll
    for (int i = 0; i < 4; ++i)
        *(u32x4*)(dst + i * 8) = *(const u32x4*)&sT[ch * 136 + po + i * 8];
}

// ---------------------------------------------------------------------------
// Proj GEMM (M=128) with fused partial-combine: A = (O1+O2)/(l1+l2) staged.
// Wave w owns row-tiles {2w, 2w+1}; per iter 2 A-frags x 4 B-frags -> 8 MFMA.
// ---------------------------------------------------------------------------
__global__ __launch_bounds__(256)
void proj_gemm(const _Float16* __restrict__ opart, const float* __restrict__ lpart,
               const _Float16* __restrict__ Wt, const float* __restrict__ bias,
               const float* __restrict__ resid, float* __restrict__ out)
{
    __shared__ _Float16 smem[7680];    // sA[128][40] | sB[64][40]
    _Float16* sB = smem + 5120;

    const int tid  = threadIdx.x;
    const int w    = tid >> 6;
    const int lane = tid & 63;
    const int quad = lane >> 4;
    const int l16  = lane & 15;
    const int m0   = blockIdx.x * 128;
    const int n0   = blockIdx.y * 64;
    const int rA = tid >> 1, cA = (tid & 1) << 4;
    const int rB = tid >> 2, cB = (tid & 3) << 3;

    const _Float16* o1p = opart;
    const _Float16* o2p = opart + 8388608;
    const int row = m0 + rA;
    const float inv = 1.0f / (lpart[row] + lpart[32768 + row]);

    u32x4 a1v = *(const u32x4*)(o1p + (size_t)row * 256 + cA);
    u32x4 a1w = *(const u32x4*)(o1p + (size_t)row * 256 + cA + 8);
    u32x4 a2v = *(const u32x4*)(o2p + (size_t)row * 256 + cA);
    u32x4 a2w = *(const u32x4*)(o2p + (size_t)row * 256 + cA + 8);
    u32x4 bst = *(const u32x4*)(Wt + (size_t)(n0 + rB) * 256 + cB);

    f32x4 zero4 = {0.f, 0.f, 0.f, 0.f};
    f32x4 acc[2][4];
#pragma unroll
    for (int m = 0; m < 2; ++m)
#pragma unroll
        for (int nt = 0; nt < 4; ++nt) acc[m][nt] = zero4;

    for (int it = 0; it < 8; ++it) {
        __syncthreads();
        {
            half8 h1 = *(half8*)&a1v, h2 = *(half8*)&a2v, t;
#pragma unroll
            for (int j = 0; j < 8; ++j)
                t[j] = (_Float16)(((float)h1[j] + (float)h2[j]) * inv);
            *(half8*)&smem[rA * 40 + cA] = t;
            half8 g1 = *(half8*)&a1w, g2 = *(half8*)&a2w, u;
#pragma unroll
            for (int j = 0; j < 8; ++j)
                u[j] = (_Float16)(((float)g1[j] + (float)g2[j]) * inv);
            *(half8*)&smem[rA * 40 + cA + 8] = u;
        }
        *(u32x4*)&sB[rB * 40 + cB] = bst;
        __syncthreads();
        if (it < 7) {
            int k0 = (it + 1) * 32;
            a1v = *(const u32x4*)(o1p + (size_t)row * 256 + k0 + cA);
            a1w = *(const u32x4*)(o1p + (size_t)row * 256 + k0 + cA + 8);
            a2v = *(const u32x4*)(o2p + (size_t)row * 256 + k0 + cA);
            a2w = *(const u32x4*)(o2p + (size_t)row * 256 + k0 + cA + 8);
            bst = *(const u32x4*)(Wt + (size_t)(n0 + rB) * 256 + k0 + cB);
        }
        half8 af[2];
#pragma unroll
        for (int m = 0; m < 2; ++m)
            af[m] = *(const half8*)&smem[((2 * w + m) * 16 + l16) * 40 + quad * 8];
#pragma unroll
        for (int nt = 0; nt < 4; ++nt) {
            half8 bf = *(const half8*)&sB[(nt * 16 + l16) * 40 + quad * 8];
#pragma unroll
            for (int m = 0; m < 2; ++m)
                acc[m][nt] = MFMA16(af[m], bf, acc[m][nt]);
        }
    }
#pragma unroll
    for (int m = 0; m < 2; ++m)
#pragma unroll
        for (int nt = 0; nt < 4; ++nt) {
#pragma unroll
            for (int reg = 0; reg < 4; ++reg) {
                int orow = m0 + (2 * w + m) * 16 + quad * 4 + reg;
                int col = n0 + nt * 16 + l16;
                out[(size_t)orow * 256 + col] =
                    acc[m][nt][reg] + bias[col] + resid[(size_t)orow * 256 + col];
            }
        }
}

// ---------------------------------------------------------------------------
// Flash attention, 32x32x16 f16, 32 Q-rows/wave, 8 waves. Grid 256.
// XCD swizzle (R8, FETCH 82->33MB): xcd=bid&7, idx=bid>>3, g=xcd+8*(idx&1),
// qg=idx>>1, b=g>>1, kh=g&1 - all 16 sharers of a (b,kh) K/V stream on 1 XCD.
// 1 block/CU, 2 waves/SIMD. 64 kt of 32 keys.
// R12: ring-3 LDS (98304 B): sK[3][16384] | sV[3][16384], 2-deep prefetch,
// counted vmcnt: per iter "s_waitcnt vmcnt(4); s_barrier" - tile kt+1's 4
// DMA loads stay in flight across the barrier (never drain to 0 mid-loop).
// WAR: buffer (kt+2)%3 overwritten at iter kt was read at iter kt-1, all
// reads complete pre-barrier; ds_reads consumed by MFMAs pre-barrier.
// Read-order slabs: K slab s: lane l holds K[key=l&31][ch=16s+8*(l>>5)..+7];
// V slab (ct,ks): lane l holds V[key=16ks+8*(l>>5)..+7][ch=32ct+(l&31)].
// S^T: A=K, B=Q resident; 2 interleaved acc chains saA/saB.
// P in registers: cvt_pkrtz pairs; permlane32_swap -> pf0 (keys 0-15), pf1
// (16-31). Split-softmax interleaved with PV k-steps; setprio around MFMA.
// ---------------------------------------------------------------------------
__global__ __launch_bounds__(512, 2)
void attn_kernel(const _Float16* __restrict__ q, const _Float16* __restrict__ k,
                 const _Float16* __restrict__ vt, _Float16* __restrict__ opart,
                 float* __restrict__ lpart)
{
    extern __shared__ char smem[];
    char* sKb = smem;             // [3][16384]
    char* sVb = smem + 49152;     // [3][16384]

    const int tid  = threadIdx.x;
    const int w    = tid >> 6;    // 0..7
    const int lane = tid & 63;
    const int l31  = lane & 31;
    const int hi   = lane >> 5;
    // XCD-locality swizzle (bijective): all 16 sharers of (b,kh) on one XCD.
    const int bid  = blockIdx.x;
    const int xcd  = bid & 7, idx = bid >> 3;
    const int g    = xcd + 8 * (idx & 1);
    const int qg   = idx >> 1;
    const int b    = g >> 1;
    const int kh   = g & 1;

    const _Float16* kb = k  + (size_t)b * 1048576 + (size_t)kh * 524288;
    const _Float16* vb = vt + (size_t)b * 1048576 + kh * 2048;
    const int rowbase = qg * 256 + w * 32;

    // Q resident: qf[s] = Q[row = rowbase + l31][ch=16s+8hi..+7]
    half8 qf[16];
    {
        const _Float16* q0 = q + (size_t)(b * 4096 + rowbase + l31) * 256 + hi * 8;
#pragma unroll
        for (int s = 0; s < 16; ++s) qf[s] = *(const half8*)(q0 + s * 16);
    }

    f32x16 o[8];
#pragma unroll
    for (int i = 0; i < 8; ++i)
#pragma unroll
        for (int j = 0; j < 16; ++j) o[i][j] = 0.f;
    float ls = 0.f;

    const int koffL = l31 * 256 + hi * 8;    // K DMA src (+ s*16 per slab)

    // stage tile t (4 loads/wave: 2 K slabs + 2 V slabs) into buffers dK,dV
    auto stage = [&](int t, char* dK, char* dV) {
        const _Float16* ktb = kb + (size_t)t * 8192;
        const _Float16* vtb = vb + t * 32;
#pragma unroll
        for (int j = 0; j < 2; ++j) {
            int s = w * 2 + j;
            lds_load16(ktb + koffL + s * 16, dK + s * 1024);
            int ct = s >> 1, ks = s & 1;
            lds_load16(vtb + (size_t)(32 * ct + l31) * 4096 + 16 * ks + 8 * hi,
                       dV + s * 1024);
        }
    };

    // prologue: tiles 0 and 1 in flight (8 outstanding loads/wave)
    stage(0, sKb, sVb);
    stage(1, sKb + 16384, sVb + 16384);

    int cur = 0;   // ring-3 buffer holding tile kt
    for (int kt = 0; kt < 64; ++kt) {
        // counted drain: tile kt's 4 loads done; tile kt+1's stay in flight.
        if (kt < 63) { __asm__ volatile("s_waitcnt vmcnt(4)" ::: "memory"); }
        else         { __asm__ volatile("s_waitcnt vmcnt(0)" ::: "memory"); }
        __builtin_amdgcn_s_barrier();   // all waves' tile-kt slabs published

        if (kt < 62) {                  // 2-deep prefetch into freed buffer
            int nb = cur + 2; if (nb >= 3) nb -= 3;
            stage(kt + 2, sKb + nb * 16384, sVb + nb * 16384);
        }

        const char* K = sKb + cur * 16384;
        const char* V = sVb + cur * 16384;

        // ---- S^T = K Q^T : 32 keys x 32 qrows, 16 ch-steps, 2 acc chains
        f32x16 saA, saB;
#pragma unroll
        for (int j = 0; j < 16; ++j) { saA[j] = 0.f; saB[j] = 0.f; }
        __builtin_amdgcn_s_setprio(1);
#pragma unroll
        for (int s = 0; s < 16; s += 2) {
            half8 a0 = *(const half8*)(K + s * 1024 + lane * 16);
            half8 a1 = *(const half8*)(K + (s + 1) * 1024 + lane * 16);
            saA = MFMA32(a0, qf[s], saA);
            saB = MFMA32(a1, qf[s + 1], saB);
        }
        __builtin_amdgcn_s_setprio(0);

        // ---- softmax half 0 (keys 0-15) -> pf0
        unsigned int c[8];
#pragma unroll
        for (int j = 0; j < 8; ++j) saA[j] += saB[j];
#pragma unroll
        for (int qq = 0; qq < 2; ++qq) {
            float p0 = EXP2(saA[qq * 4 + 0] - ESHIFT);
            float p1 = EXP2(saA[qq * 4 + 1] - ESHIFT);
            float p2 = EXP2(saA[qq * 4 + 2] - ESHIFT);
            float p3 = EXP2(saA[qq * 4 + 3] - ESHIFT);
            ls += (p0 + p1) + (p2 + p3);
            c[2 * qq]     = __builtin_bit_cast(unsigned int,
                                __builtin_amdgcn_cvt_pkrtz(p0, p1));
            c[2 * qq + 1] = __builtin_bit_cast(unsigned int,
                                __builtin_amdgcn_cvt_pkrtz(p2, p3));
        }
        u32x2 s0 = __builtin_amdgcn_permlane32_swap(c[0], c[2], false, false);
        u32x2 s1 = __builtin_amdgcn_permlane32_swap(c[1], c[3], false, false);
        u32x4 w0 = {s0[0], s1[0], s0[1], s1[1]};
        half8 pf0 = __builtin_bit_cast(half8, w0);   // keys 0-15

        // ---- PV k-step 0: O += P[:,0:16] V[0:16,:]
        __builtin_amdgcn_s_setprio(1);
#pragma unroll
        for (int ct = 0; ct < 8; ++ct) {
            half8 b0 = *(const half8*)(V + (ct * 2 + 0) * 1024 + lane * 16);
            o[ct] = MFMA32(pf0, b0, o[ct]);
        }
        __builtin_amdgcn_s_setprio(0);

        // ---- softmax half 1 (keys 16-31) -> pf1
#pragma unroll
        for (int j = 8; j < 16; ++j) saA[j] += saB[j];
#pragma unroll
        for (int qq = 2; qq < 4; ++qq) {
            float p0 = EXP2(saA[qq * 4 + 0] - ESHIFT);
            float p1 = EXP2(saA[qq * 4 + 1] - ESHIFT);
            float p2 = EXP2(saA[qq * 4 + 2] - ESHIFT);
            float p3 = EXP2(saA[qq * 4 + 3] - ESHIFT);
            ls += (p0 + p1) + (p2 + p3);
            c[2 * qq]     = __builtin_bit_cast(unsigned int,
                                __builtin_amdgcn_cvt_pkrtz(p0, p1));
            c[2 * qq + 1] = __builtin_bit_cast(unsigned int,
                                __builtin_amdgcn_cvt_pkrtz(p2, p3));
        }
        u32x2 s2 = __builtin_amdgcn_permlane32_swap(c[4], c[6], false, false);
        u32x2 s3 = __builtin_amdgcn_permlane32_swap(c[5], c[7], false, false);
        u32x4 w1 = {s2[0], s3[0], s2[1], s3[1]};
        half8 pf1 = __builtin_bit_cast(half8, w1);   // keys 16-31

        // ---- PV k-step 1: O += P[:,16:32] V[16:32,:]
        __builtin_amdgcn_s_setprio(1);
#pragma unroll
        for (int ct = 0; ct < 8; ++ct) {
            half8 b1 = *(const half8*)(V + (ct * 2 + 1) * 1024 + lane * 16);
            o[ct] = MFMA32(pf1, b1, o[ct]);
        }
        __builtin_amdgcn_s_setprio(0);

        cur = (cur + 1 == 3) ? 0 : cur + 1;
    }

    // ---- epilogue: combine l across hi-halves, store unnormalized O + l
    ls += __shfl_xor(ls, 32);
    _Float16* po = opart + (size_t)kh * 8388608 + (size_t)(b * 4096 + rowbase) * 256;
    float* pl = lpart + kh * 32768 + b * 4096 + rowbase;
    if (hi == 0) pl[l31] = ls;
#pragma unroll
    for (int ct = 0; ct < 8; ++ct) {
#pragma unroll
        for (int reg = 0; reg < 16; ++reg) {
            int row = (reg & 3) + 8 * (reg >> 2) + 4 * hi;
            po[(size_t)row * 256 + ct * 32 + l31] = (_Float16)o[ct][reg];
        }
    }
}

// ---------------------------------------------------------------------------
extern "C" void kernel_launch(void* const* d_in, const int* in_sizes, int n_in,
                              void* d_out, int out_size, void* d_ws, size_t ws_size,
                              hipStream_t stream) {
    const float* x  = (const float*)d_in[0];
    const float* wq = (const float*)d_in[1];
    const float* bq = (const float*)d_in[2];
    const float* wk = (const float*)d_in[3];
    const float* bk = (const float*)d_in[4];
    const float* wv = (const float*)d_in[5];
    const float* bv = (const float*)d_in[6];
    const float* wp = (const float*)d_in[7];
    const float* bp = (const float*)d_in[8];

    _Float16* qws  = (_Float16*)d_ws;
    _Float16* kws  = qws + 8388608;
    _Float16* vtws = kws + 8388608;
    _Float16* ows  = vtws + 8388608;            // 2 x 8388608 halves (partials)
    _Float16* wt   = ows + 16777216;            // 4 x 65536 halves
    float*    lws  = (float*)(wt + 262144);     // 2 x 32768 f32

    dim3 blk(256);

    (void)hipFuncSetAttribute((const void*)attn_kernel,
                              hipFuncAttributeMaxDynamicSharedMemorySize, 98304);

    wt_prep<<<dim3(4, 4, 4), blk, 0, stream>>>(wq, wk, wv, wp, wt);
    qkv_gemm<<<dim3(256, 4), blk, 0, stream>>>(x, wt, bq, bk, bv, qws, kws, vtws);
    attn_kernel<<<dim3(256), dim3(512), 98304, stream>>>(qws, kws, vtws, ows, lws);
    proj_gemm<<<dim3(256, 4), blk, 0, stream>>>(ows, lws, wt + 196608, bp, x, (float*)d_out);
}

// Round 13
// 278.153 us; speedup vs baseline: 1.0161x; 1.0161x over previous
//
#include <hip/hip_runtime.h>

// AttentionBlock: B=8, N=4096, C=256, fp32 in/out.
// Pipeline: [wt_prep][qkv gemm f16][flash attn 32x32x16 f16][proj gemm+combine]
// R13 FINAL = R9/R11 configuration (best verified: 278.3/281.7us, 2 repros).
// Kept: 2 waves/SIMD (R1 +27%); in-reg P via permlane (R3); M=128 GEMM tile
// (R6); XCD swizzle (R8, FETCH 82->33MB); split-softmax+setprio (R7, neutral
// but cleaner liveness).
// Falsified: B-from-global (R4 -16us), 2x256 block-split (R5 -25us), GEMM
// dbuf (R8 -12us), 4 waves/SIMD (R10 full-acc spill, 10x), counted-vmcnt
// ring-3 (R12 -4us: DMA completes within the 4600cyc iter; drain never
// stalls), 64-key tiles (R2 spill). Attn floor = lockstep S^T->softmax->PV
// chain at 2 waves/SIMD (MFMA 2048/4600 cyc = 44% MfmaUtil, ~930 TF =
// plain-HIP flash-attn plateau); past it needs a co-designed 4-cluster
// role-split schedule (ground-up rewrite).
// Workspace: q 16MB | k 16MB | vt 16MB | opart f16 32MB | wt 512KB | l 256KB

typedef _Float16 half8 __attribute__((ext_vector_type(8)));
typedef _Float16 half4 __attribute__((ext_vector_type(4)));
typedef float f32x4 __attribute__((ext_vector_type(4)));
typedef float f32x16 __attribute__((ext_vector_type(16)));
typedef unsigned int u32x4 __attribute__((ext_vector_type(4)));
typedef unsigned int u32x2 __attribute__((ext_vector_type(2)));

#define MFMA16(a, b, c) __builtin_amdgcn_mfma_f32_16x16x32_f16((a), (b), (c), 0, 0, 0)
#define MFMA32(a, b, c) __builtin_amdgcn_mfma_f32_32x32x16_f16((a), (b), (c), 0, 0, 0)

#if __has_builtin(__builtin_amdgcn_exp2f)
#define EXP2(x) __builtin_amdgcn_exp2f(x)
#else
#define EXP2(x) exp2f(x)
#endif

// log2(e)/16 folded into q; exp(s-8) == exp2(s' - 8*log2e)
#define QSCALE 0.09016843898f
#define ESHIFT 11.5415603f

__device__ __forceinline__ void lds_load16(const void* g, void* l) {
    __builtin_amdgcn_global_load_lds(
        (const __attribute__((address_space(1))) unsigned int*)g,
        (__attribute__((address_space(3))) unsigned int*)l, 16, 0, 0);
}

// ---------------------------------------------------------------------------
// Weight prep: Wt[z][n][k] f16 = W_z[k][n] f32, 4 weights of 256x256.
// ---------------------------------------------------------------------------
__global__ __launch_bounds__(256)
void wt_prep(const float* __restrict__ w0, const float* __restrict__ w1,
             const float* __restrict__ w2, const float* __restrict__ w3,
             _Float16* __restrict__ outw)
{
    __shared__ _Float16 sT[64 * 72];
    const int z = blockIdx.z;
    const float* W = (z == 0) ? w0 : (z == 1) ? w1 : (z == 2) ? w2 : w3;
    _Float16* O = outw + z * 65536;
    const int kb = blockIdx.x * 64, nb = blockIdx.y * 64;
    const int t = threadIdx.x;
    const int r = t >> 4, c4 = (t & 15) * 4;
#pragma unroll
    for (int i = 0; i < 4; ++i) {
        f32x4 ld = *(const f32x4*)(W + (size_t)(kb + r + i * 16) * 256 + nb + c4);
#pragma unroll
        for (int j = 0; j < 4; ++j) sT[(c4 + j) * 72 + r + i * 16] = (_Float16)ld[j];
    }
    __syncthreads();
#pragma unroll
    for (int i = 0; i < 4; ++i) {
        int n = r + i * 16;
        *(u32x2*)&O[(size_t)(nb + n) * 256 + kb + c4] = *(const u32x2*)&sT[n * 72 + c4];
    }
}

// ---------------------------------------------------------------------------
// Fused QKV GEMM (M=128): x f32 -> q,k f16 row-major; v -> f16 vt[b][ch][pix].
// Per iter: stage A 128x32 + 3x B 64x32 into LDS (2 barriers), then per wave
// 8 A-frags x 3 B-frags -> 24 MFMA16. Wave w owns col-tile w of all 3 outputs.
// ---------------------------------------------------------------------------
__global__ __launch_bounds__(256)
void qkv_gemm(const float* __restrict__ x, const _Float16* __restrict__ wt,
              const float* __restrict__ bq, const float* __restrict__ bk,
              const float* __restrict__ bv,
              _Float16* __restrict__ qo, _Float16* __restrict__ ko,
              _Float16* __restrict__ vo)
{
    __shared__ _Float16 smem[12800];   // sA[128][40] | 3 x sB[64][40]

    const int tid  = threadIdx.x;
    const int w    = tid >> 6;
    const int lane = tid & 63;
    const int quad = lane >> 4;
    const int l16  = lane & 15;
    const int m0   = blockIdx.x * 128;
    const int n0   = blockIdx.y * 64;
    const int rA = tid >> 1, cA = (tid & 1) << 4;   // A staging: 2 thr/row, 16 ch
    const int rB = tid >> 2, cB = (tid & 3) << 3;   // B staging: 4 thr/row, 8 ch

    const float* ap = x + (size_t)(m0 + rA) * 256 + cA;
    f32x4 a0 = *(const f32x4*)ap,       a1 = *(const f32x4*)(ap + 4);
    f32x4 a2 = *(const f32x4*)(ap + 8), a3 = *(const f32x4*)(ap + 12);
    u32x4 bst[3];
#pragma unroll
    for (int o = 0; o < 3; ++o)
        bst[o] = *(const u32x4*)(wt + o * 65536 + (size_t)(n0 + rB) * 256 + cB);

    f32x4 zero4 = {0.f, 0.f, 0.f, 0.f};
    f32x4 acc[3][8];
#pragma unroll
    for (int o = 0; o < 3; ++o)
#pragma unroll
        for (int mt = 0; mt < 8; ++mt) acc[o][mt] = zero4;

    for (int it = 0; it < 8; ++it) {
        __syncthreads();
        half8 t0, t1;
#pragma unroll
        for (int j = 0; j < 4; ++j) {
            t0[j] = (_Float16)a0[j]; t0[j + 4] = (_Float16)a1[j];
            t1[j] = (_Float16)a2[j]; t1[j + 4] = (_Float16)a3[j];
        }
        *(half8*)&smem[rA * 40 + cA]     = t0;
        *(half8*)&smem[rA * 40 + cA + 8] = t1;
#pragma unroll
        for (int o = 0; o < 3; ++o)
            *(u32x4*)&smem[5120 + o * 2560 + rB * 40 + cB] = bst[o];
        __syncthreads();
        if (it < 7) {
            int k0 = (it + 1) * 32;
            const float* ap2 = x + (size_t)(m0 + rA) * 256 + k0 + cA;
            a0 = *(const f32x4*)ap2;       a1 = *(const f32x4*)(ap2 + 4);
            a2 = *(const f32x4*)(ap2 + 8); a3 = *(const f32x4*)(ap2 + 12);
#pragma unroll
            for (int o = 0; o < 3; ++o)
                bst[o] = *(const u32x4*)(wt + o * 65536 + (size_t)(n0 + rB) * 256 + k0 + cB);
        }
        half8 af[8];
#pragma unroll
        for (int mt = 0; mt < 8; ++mt)
            af[mt] = *(const half8*)&smem[(mt * 16 + l16) * 40 + quad * 8];
#pragma unroll
        for (int o = 0; o < 3; ++o) {
            half8 bf = *(const half8*)&smem[5120 + o * 2560 + (16 * w + l16) * 40 + quad * 8];
#pragma unroll
            for (int mt = 0; mt < 8; ++mt)
                acc[o][mt] = MFMA16(af[mt], bf, acc[o][mt]);
        }
    }

    const int col = n0 + 16 * w + l16;
#pragma unroll
    for (int mt = 0; mt < 8; ++mt) {
#pragma unroll
        for (int reg = 0; reg < 4; ++reg) {
            int row = m0 + 16 * mt + quad * 4 + reg;
            qo[(size_t)row * 256 + col] = (_Float16)((acc[0][mt][reg] + bq[col]) * QSCALE);
            ko[(size_t)row * 256 + col] = (_Float16)(acc[1][mt][reg] + bk[col]);
        }
    }
    __syncthreads();
    _Float16* sT = smem;   // 64 ch x 128 pix transpose staging (stride 136)
#pragma unroll
    for (int mt = 0; mt < 8; ++mt)
#pragma unroll
        for (int reg = 0; reg < 4; ++reg)
            sT[(16 * w + l16) * 136 + 16 * mt + quad * 4 + reg] =
                (_Float16)(acc[2][mt][reg] + bv[col]);
    __syncthreads();
    int ch = tid >> 2, po = (tid & 3) << 5;
    int bb = m0 >> 12, pix = m0 & 4095;
    _Float16* dst = vo + (size_t)bb * 1048576 + (size_t)(n0 + ch) * 4096 + pix + po;
#pragma unroll
    for (int i = 0; i < 4; ++i)
        *(u32x4*)(dst + i * 8) = *(const u32x4*)&sT[ch * 136 + po + i * 8];
}

// ---------------------------------------------------------------------------
// Proj GEMM (M=128) with fused partial-combine: A = (O1+O2)/(l1+l2) staged.
// Wave w owns row-tiles {2w, 2w+1}; per iter 2 A-frags x 4 B-frags -> 8 MFMA.
// ---------------------------------------------------------------------------
__global__ __launch_bounds__(256)
void proj_gemm(const _Float16* __restrict__ opart, const float* __restrict__ lpart,
               const _Float16* __restrict__ Wt, const float* __restrict__ bias,
               const float* __restrict__ resid, float* __restrict__ out)
{
    __shared__ _Float16 smem[7680];    // sA[128][40] | sB[64][40]
    _Float16* sB = smem + 5120;

    const int tid  = threadIdx.x;
    const int w    = tid >> 6;
    const int lane = tid & 63;
    const int quad = lane >> 4;
    const int l16  = lane & 15;
    const int m0   = blockIdx.x * 128;
    const int n0   = blockIdx.y * 64;
    const int rA = tid >> 1, cA = (tid & 1) << 4;
    const int rB = tid >> 2, cB = (tid & 3) << 3;

    const _Float16* o1p = opart;
    const _Float16* o2p = opart + 8388608;
    const int row = m0 + rA;
    const float inv = 1.0f / (lpart[row] + lpart[32768 + row]);

    u32x4 a1v = *(const u32x4*)(o1p + (size_t)row * 256 + cA);
    u32x4 a1w = *(const u32x4*)(o1p + (size_t)row * 256 + cA + 8);
    u32x4 a2v = *(const u32x4*)(o2p + (size_t)row * 256 + cA);
    u32x4 a2w = *(const u32x4*)(o2p + (size_t)row * 256 + cA + 8);
    u32x4 bst = *(const u32x4*)(Wt + (size_t)(n0 + rB) * 256 + cB);

    f32x4 zero4 = {0.f, 0.f, 0.f, 0.f};
    f32x4 acc[2][4];
#pragma unroll
    for (int m = 0; m < 2; ++m)
#pragma unroll
        for (int nt = 0; nt < 4; ++nt) acc[m][nt] = zero4;

    for (int it = 0; it < 8; ++it) {
        __syncthreads();
        {
            half8 h1 = *(half8*)&a1v, h2 = *(half8*)&a2v, t;
#pragma unroll
            for (int j = 0; j < 8; ++j)
                t[j] = (_Float16)(((float)h1[j] + (float)h2[j]) * inv);
            *(half8*)&smem[rA * 40 + cA] = t;
            half8 g1 = *(half8*)&a1w, g2 = *(half8*)&a2w, u;
#pragma unroll
            for (int j = 0; j < 8; ++j)
                u[j] = (_Float16)(((float)g1[j] + (float)g2[j]) * inv);
            *(half8*)&smem[rA * 40 + cA + 8] = u;
        }
        *(u32x4*)&sB[rB * 40 + cB] = bst;
        __syncthreads();
        if (it < 7) {
            int k0 = (it + 1) * 32;
            a1v = *(const u32x4*)(o1p + (size_t)row * 256 + k0 + cA);
            a1w = *(const u32x4*)(o1p + (size_t)row * 256 + k0 + cA + 8);
            a2v = *(const u32x4*)(o2p + (size_t)row * 256 + k0 + cA);
            a2w = *(const u32x4*)(o2p + (size_t)row * 256 + k0 + cA + 8);
            bst = *(const u32x4*)(Wt + (size_t)(n0 + rB) * 256 + k0 + cB);
        }
        half8 af[2];
#pragma unroll
        for (int m = 0; m < 2; ++m)
            af[m] = *(const half8*)&smem[((2 * w + m) * 16 + l16) * 40 + quad * 8];
#pragma unroll
        for (int nt = 0; nt < 4; ++nt) {
            half8 bf = *(const half8*)&sB[(nt * 16 + l16) * 40 + quad * 8];
#pragma unroll
            for (int m = 0; m < 2; ++m)
                acc[m][nt] = MFMA16(af[m], bf, acc[m][nt]);
        }
    }
#pragma unroll
    for (int m = 0; m < 2; ++m)
#pragma unroll
        for (int nt = 0; nt < 4; ++nt) {
#pragma unroll
            for (int reg = 0; reg < 4; ++reg) {
                int orow = m0 + (2 * w + m) * 16 + quad * 4 + reg;
                int col = n0 + nt * 16 + l16;
                out[(size_t)orow * 256 + col] =
                    acc[m][nt][reg] + bias[col] + resid[(size_t)orow * 256 + col];
            }
        }
}

// ---------------------------------------------------------------------------
// Flash attention, 32x32x16 f16, 32 Q-rows/wave, 8 waves. Grid 256.
// XCD swizzle (R8, FETCH 82->33MB): xcd=bid&7, idx=bid>>3, g=xcd+8*(idx&1),
// qg=idx>>1, b=g>>1, kh=g&1 - all 16 sharers of a (b,kh) K/V stream on 1 XCD.
// 1 block/CU, 2 waves/SIMD. 64 kt of 32 keys, double-buffered.
// LDS (65536 B): sK[2][16384] | sV[2][16384].
// Read-order slabs: K slab s: lane l holds K[key=l&31][ch=16s+8*(l>>5)..+7];
// V slab (ct,ks): lane l holds V[key=16ks+8*(l>>5)..+7][ch=32ct+(l&31)].
// S^T: A=K, B=Q resident; 2 interleaved acc chains saA/saB.
// P in registers: cvt_pkrtz pairs; permlane32_swap -> pf0 (keys 0-15), pf1
// (16-31). Split-softmax interleaved with PV k-steps; setprio around MFMA.
// ---------------------------------------------------------------------------
__global__ __launch_bounds__(512, 2)
void attn_kernel(const _Float16* __restrict__ q, const _Float16* __restrict__ k,
                 const _Float16* __restrict__ vt, _Float16* __restrict__ opart,
                 float* __restrict__ lpart)
{
    extern __shared__ char smem[];
    char* sKb = smem;             // [2][16384]
    char* sVb = smem + 32768;     // [2][16384]

    const int tid  = threadIdx.x;
    const int w    = tid >> 6;    // 0..7
    const int lane = tid & 63;
    const int l31  = lane & 31;
    const int hi   = lane >> 5;
    // XCD-locality swizzle (bijective): all 16 sharers of (b,kh) on one XCD.
    const int bid  = blockIdx.x;
    const int xcd  = bid & 7, idx = bid >> 3;
    const int g    = xcd + 8 * (idx & 1);
    const int qg   = idx >> 1;
    const int b    = g >> 1;
    const int kh   = g & 1;

    const _Float16* kb = k  + (size_t)b * 1048576 + (size_t)kh * 524288;
    const _Float16* vb = vt + (size_t)b * 1048576 + kh * 2048;
    const int rowbase = qg * 256 + w * 32;

    // Q resident: qf[s] = Q[row = rowbase + l31][ch=16s+8hi..+7]
    half8 qf[16];
    {
        const _Float16* q0 = q + (size_t)(b * 4096 + rowbase + l31) * 256 + hi * 8;
#pragma unroll
        for (int s = 0; s < 16; ++s) qf[s] = *(const half8*)(q0 + s * 16);
    }

    f32x16 o[8];
#pragma unroll
    for (int i = 0; i < 8; ++i)
#pragma unroll
        for (int j = 0; j < 16; ++j) o[i][j] = 0.f;
    float ls = 0.f;

    const int koffL = l31 * 256 + hi * 8;    // K DMA src (+ s*16 per slab)

    // stage tile 0 -> buf 0 (per wave: 2 K slabs + 2 V slabs)
#pragma unroll
    for (int j = 0; j < 2; ++j) {
        int s = w * 2 + j;
        lds_load16(kb + koffL + s * 16, sKb + s * 1024);
        int ct = s >> 1, ks = s & 1;
        lds_load16(vb + (size_t)(32 * ct + l31) * 4096 + 16 * ks + 8 * hi,
                   sVb + s * 1024);
    }

    for (int kt = 0; kt < 64; ++kt) {
        const int p = kt & 1;
        __syncthreads();   // publishes tile kt (drains DMA)

        if (kt < 63) {     // prefetch tile kt+1 into the other buffer
            const _Float16* ktb = kb + (size_t)(kt + 1) * 8192;
            const _Float16* vtb = vb + (kt + 1) * 32;
            char* dK = sKb + (1 - p) * 16384;
            char* dV = sVb + (1 - p) * 16384;
#pragma unroll
            for (int j = 0; j < 2; ++j) {
                int s = w * 2 + j;
                lds_load16(ktb + koffL + s * 16, dK + s * 1024);
                int ct = s >> 1, ks = s & 1;
                lds_load16(vtb + (size_t)(32 * ct + l31) * 4096 + 16 * ks + 8 * hi,
                           dV + s * 1024);
            }
        }

        const char* K = sKb + p * 16384;
        const char* V = sVb + p * 16384;

        // ---- S^T = K Q^T : 32 keys x 32 qrows, 16 ch-steps, 2 acc chains
        f32x16 saA, saB;
#pragma unroll
        for (int j = 0; j < 16; ++j) { saA[j] = 0.f; saB[j] = 0.f; }
        __builtin_amdgcn_s_setprio(1);
#pragma unroll
        for (int s = 0; s < 16; s += 2) {
            half8 a0 = *(const half8*)(K + s * 1024 + lane * 16);
            half8 a1 = *(const half8*)(K + (s + 1) * 1024 + lane * 16);
            saA = MFMA32(a0, qf[s], saA);
            saB = MFMA32(a1, qf[s + 1], saB);
        }
        __builtin_amdgcn_s_setprio(0);

        // ---- softmax half 0 (keys 0-15) -> pf0
        unsigned int c[8];
#pragma unroll
        for (int j = 0; j < 8; ++j) saA[j] += saB[j];
#pragma unroll
        for (int qq = 0; qq < 2; ++qq) {
            float p0 = EXP2(saA[qq * 4 + 0] - ESHIFT);
            float p1 = EXP2(saA[qq * 4 + 1] - ESHIFT);
            float p2 = EXP2(saA[qq * 4 + 2] - ESHIFT);
            float p3 = EXP2(saA[qq * 4 + 3] - ESHIFT);
            ls += (p0 + p1) + (p2 + p3);
            c[2 * qq]     = __builtin_bit_cast(unsigned int,
                                __builtin_amdgcn_cvt_pkrtz(p0, p1));
            c[2 * qq + 1] = __builtin_bit_cast(unsigned int,
                                __builtin_amdgcn_cvt_pkrtz(p2, p3));
        }
        u32x2 s0 = __builtin_amdgcn_permlane32_swap(c[0], c[2], false, false);
        u32x2 s1 = __builtin_amdgcn_permlane32_swap(c[1], c[3], false, false);
        u32x4 w0 = {s0[0], s1[0], s0[1], s1[1]};
        half8 pf0 = __builtin_bit_cast(half8, w0);   // keys 0-15

        // ---- PV k-step 0: O += P[:,0:16] V[0:16,:]
        __builtin_amdgcn_s_setprio(1);
#pragma unroll
        for (int ct = 0; ct < 8; ++ct) {
            half8 b0 = *(const half8*)(V + (ct * 2 + 0) * 1024 + lane * 16);
            o[ct] = MFMA32(pf0, b0, o[ct]);
        }
        __builtin_amdgcn_s_setprio(0);

        // ---- softmax half 1 (keys 16-31) -> pf1
#pragma unroll
        for (int j = 8; j < 16; ++j) saA[j] += saB[j];
#pragma unroll
        for (int qq = 2; qq < 4; ++qq) {
            float p0 = EXP2(saA[qq * 4 + 0] - ESHIFT);
            float p1 = EXP2(saA[qq * 4 + 1] - ESHIFT);
            float p2 = EXP2(saA[qq * 4 + 2] - ESHIFT);
            float p3 = EXP2(saA[qq * 4 + 3] - ESHIFT);
            ls += (p0 + p1) + (p2 + p3);
            c[2 * qq]     = __builtin_bit_cast(unsigned int,
                                __builtin_amdgcn_cvt_pkrtz(p0, p1));
            c[2 * qq + 1] = __builtin_bit_cast(unsigned int,
                                __builtin_amdgcn_cvt_pkrtz(p2, p3));
        }
        u32x2 s2 = __builtin_amdgcn_permlane32_swap(c[4], c[6], false, false);
        u32x2 s3 = __builtin_amdgcn_permlane32_swap(c[5], c[7], false, false);
        u32x4 w1 = {s2[0], s3[0], s2[1], s3[1]};
        half8 pf1 = __builtin_bit_cast(half8, w1);   // keys 16-31

        // ---- PV k-step 1: O += P[:,16:32] V[16:32,:]
        __builtin_amdgcn_s_setprio(1);
#pragma unroll
        for (int ct = 0; ct < 8; ++ct) {
            half8 b1 = *(const half8*)(V + (ct * 2 + 1) * 1024 + lane * 16);
            o[ct] = MFMA32(pf1, b1, o[ct]);
        }
        __builtin_amdgcn_s_setprio(0);
    }

    // ---- epilogue: combine l across hi-halves, store unnormalized O + l
    ls += __shfl_xor(ls, 32);
    _Float16* po = opart + (size_t)kh * 8388608 + (size_t)(b * 4096 + rowbase) * 256;
    float* pl = lpart + kh * 32768 + b * 4096 + rowbase;
    if (hi == 0) pl[l31] = ls;
#pragma unroll
    for (int ct = 0; ct < 8; ++ct) {
#pragma unroll
        for (int reg = 0; reg < 16; ++reg) {
            int row = (reg & 3) + 8 * (reg >> 2) + 4 * hi;
            po[(size_t)row * 256 + ct * 32 + l31] = (_Float16)o[ct][reg];
        }
    }
}

// ---------------------------------------------------------------------------
extern "C" void kernel_launch(void* const* d_in, const int* in_sizes, int n_in,
                              void* d_out, int out_size, void* d_ws, size_t ws_size,
                              hipStream_t stream) {
    const float* x  = (const float*)d_in[0];
    const float* wq = (const float*)d_in[1];
    const float* bq = (const float*)d_in[2];
    const float* wk = (const float*)d_in[3];
    const float* bk = (const float*)d_in[4];
    const float* wv = (const float*)d_in[5];
    const float* bv = (const float*)d_in[6];
    const float* wp = (const float*)d_in[7];
    const float* bp = (const float*)d_in[8];

    _Float16* qws  = (_Float16*)d_ws;
    _Float16* kws  = qws + 8388608;
    _Float16* vtws = kws + 8388608;
    _Float16* ows  = vtws + 8388608;            // 2 x 8388608 halves (partials)
    _Float16* wt   = ows + 16777216;            // 4 x 65536 halves
    float*    lws  = (float*)(wt + 262144);     // 2 x 32768 f32

    dim3 blk(256);

    (void)hipFuncSetAttribute((const void*)attn_kernel,
                              hipFuncAttributeMaxDynamicSharedMemorySize, 65536);

    wt_prep<<<dim3(4, 4, 4), blk, 0, stream>>>(wq, wk, wv, wp, wt);
    qkv_gemm<<<dim3(256, 4), blk, 0, stream>>>(x, wt, bq, bk, bv, qws, kws, vtws);
    attn_kernel<<<dim3(256), dim3(512), 65536, stream>>>(qws, kws, vtws, ows, lws);
    proj_gemm<<<dim3(256, 4), blk, 0, stream>>>(ows, lws, wt + 196608, bp, x, (float*)d_out);
}